// Round 4
// baseline (631.889 us; speedup 1.0000x reference)
//
#include <hip/hip_runtime.h>
#include <hip/hip_bf16.h>

#define NEG_SLOPE 0.2f

typedef __attribute__((ext_vector_type(8))) short bf16x8;
typedef __attribute__((ext_vector_type(4))) float f32x4;

static inline int cdiv(int a, int b) { return (a + b - 1) / b; }

__device__ inline unsigned short f2bf(float x) {
  __hip_bfloat16 b = __float2bfloat16(x);
  return *reinterpret_cast<unsigned short*>(&b);
}
__device__ inline float bf2f(unsigned short u) {
  __hip_bfloat16 b = *reinterpret_cast<__hip_bfloat16*>(&u);
  return __bfloat162float(b);
}
__device__ inline void fma4(float4& acc, float w, const float4& v) {
  acc.x = fmaf(w, v.x, acc.x); acc.y = fmaf(w, v.y, acc.y);
  acc.z = fmaf(w, v.z, acc.z); acc.w = fmaf(w, v.w, acc.w);
}
__device__ inline float sel4(const float4& a, int h) {
  float r = a.x;
  r = h == 1 ? a.y : r;
  r = h == 2 ? a.z : r;
  r = h == 3 ? a.w : r;
  return r;
}

// ---------------- split f32 -> bf16 hi/lo ----------------
__global__ void split_kernel(const float* __restrict__ x, unsigned short* __restrict__ hi,
                             unsigned short* __restrict__ lo, int n4) {
  int i = blockIdx.x * blockDim.x + threadIdx.x;
  if (i >= n4) return;
  float4 v = reinterpret_cast<const float4*>(x)[i];
  unsigned short h0 = f2bf(v.x), h1 = f2bf(v.y), h2 = f2bf(v.z), h3 = f2bf(v.w);
  ushort4 hv; hv.x = h0; hv.y = h1; hv.z = h2; hv.w = h3;
  ushort4 lv;
  lv.x = f2bf(v.x - bf2f(h0)); lv.y = f2bf(v.y - bf2f(h1));
  lv.z = f2bf(v.z - bf2f(h2)); lv.w = f2bf(v.w - bf2f(h3));
  reinterpret_cast<ushort4*>(hi)[i] = hv;
  reinterpret_cast<ushort4*>(lo)[i] = lv;
}

// ---------------- split + transpose W[K][Mo] -> T[Mo][K] bf16 hi/lo ----------------
__global__ void splitT_kernel(const float* __restrict__ W, unsigned short* __restrict__ hi,
                              unsigned short* __restrict__ lo, int K, int Mo) {
  int i = blockIdx.x * blockDim.x + threadIdx.x;
  if (i >= K * Mo) return;
  int k = i / Mo, m = i - k * Mo;
  float v = W[i];
  unsigned short h = f2bf(v);
  hi[(size_t)m * K + k] = h;
  lo[(size_t)m * K + k] = f2bf(v - bf2f(h));
}

// ---------------- GEMM + fused attention-score partials ----------------
// C[M][Ncols] = (Ahi+Alo)[M][K] @ (BThi+BTlo)[Ncols][K]^T ; el/er += C·al / C·ar (atomic)
template <int NF>
__global__ __launch_bounds__(256) void gemm_split(
    const unsigned short* __restrict__ Ahi, const unsigned short* __restrict__ Alo,
    const unsigned short* __restrict__ BThi, const unsigned short* __restrict__ BTlo,
    float* __restrict__ C, const float* __restrict__ alv, const float* __restrict__ arv,
    float* __restrict__ el, float* __restrict__ er, int Hn, int M, int K, int Ncols) {
  constexpr int BN = NF * 32;
  __shared__ unsigned short As[128][88];   // hi at [0,32), lo at [48,80)
  __shared__ unsigned short Bs[BN][88];
  const int tid = threadIdx.x;
  const int row0 = blockIdx.x * 128;
  const int col0 = blockIdx.y * BN;
  const int wid = tid >> 6, lane = tid & 63;
  const int wm = wid >> 1, wn = wid & 1;
  const int l15 = lane & 15, lg = lane >> 4;
  f32x4 acc[4][NF];
#pragma unroll
  for (int m = 0; m < 4; ++m)
#pragma unroll
    for (int n = 0; n < NF; ++n) acc[m][n] = (f32x4){0.f, 0.f, 0.f, 0.f};

  const uint4 zero4 = {0u, 0u, 0u, 0u};
  for (int k0 = 0; k0 < K; k0 += 32) {
    {
      int r = tid >> 2;
      const int kg = tid & 3;
#pragma unroll
      for (int it = 0; it < 2; ++it, r += 64) {
        const int grow = row0 + r;
        uint4 vh = zero4, vl = zero4;
        if (grow < M) {
          vh = *reinterpret_cast<const uint4*>(&Ahi[(size_t)grow * K + k0 + kg * 8]);
          vl = *reinterpret_cast<const uint4*>(&Alo[(size_t)grow * K + k0 + kg * 8]);
        }
        *reinterpret_cast<uint4*>(&As[r][kg * 8]) = vh;
        *reinterpret_cast<uint4*>(&As[r][48 + kg * 8]) = vl;
      }
    }
    {
      int r = tid >> 2;
      const int kg = tid & 3;
#pragma unroll
      for (int it = 0; it < BN / 64; ++it, r += 64) {
        const int gcol = col0 + r;
        uint4 vh = *reinterpret_cast<const uint4*>(&BThi[(size_t)gcol * K + k0 + kg * 8]);
        uint4 vl = *reinterpret_cast<const uint4*>(&BTlo[(size_t)gcol * K + k0 + kg * 8]);
        *reinterpret_cast<uint4*>(&Bs[r][kg * 8]) = vh;
        *reinterpret_cast<uint4*>(&Bs[r][48 + kg * 8]) = vl;
      }
    }
    __syncthreads();
    bf16x8 ah[4], al[4];
#pragma unroll
    for (int m = 0; m < 4; ++m) {
      const int row = wm * 64 + m * 16 + l15;
      ah[m] = *reinterpret_cast<const bf16x8*>(&As[row][lg * 8]);
      al[m] = *reinterpret_cast<const bf16x8*>(&As[row][48 + lg * 8]);
    }
#pragma unroll
    for (int n = 0; n < NF; ++n) {
      const int col = wn * (NF * 16) + n * 16 + l15;
      bf16x8 bh = *reinterpret_cast<const bf16x8*>(&Bs[col][lg * 8]);
      bf16x8 bl = *reinterpret_cast<const bf16x8*>(&Bs[col][48 + lg * 8]);
#pragma unroll
      for (int m = 0; m < 4; ++m) {
        acc[m][n] = __builtin_amdgcn_mfma_f32_16x16x32_bf16(ah[m], bh, acc[m][n], 0, 0, 0);
        acc[m][n] = __builtin_amdgcn_mfma_f32_16x16x32_bf16(ah[m], bl, acc[m][n], 0, 0, 0);
        acc[m][n] = __builtin_amdgcn_mfma_f32_16x16x32_bf16(al[m], bh, acc[m][n], 0, 0, 0);
      }
    }
    __syncthreads();
  }
  // wave's NF col-frags all lie in one head (NF*16 <= 64)
  const int hw = (col0 + wn * (NF * 16)) >> 6;
  float alw[NF], arw[NF];
#pragma unroll
  for (int n = 0; n < NF; ++n) {
    const int colg = col0 + wn * (NF * 16) + n * 16 + l15;
    alw[n] = alv[colg];
    arw[n] = arv[colg];
  }
  float pel[4][4] = {{0.f}}, per_[4][4] = {{0.f}};
  // epilogue: C/D layout col=lane&15, row=(lane>>4)*4+j
#pragma unroll
  for (int m = 0; m < 4; ++m) {
#pragma unroll
    for (int n = 0; n < NF; ++n) {
      const int col = col0 + wn * (NF * 16) + n * 16 + l15;
#pragma unroll
      for (int j = 0; j < 4; ++j) {
        const int row = row0 + wm * 64 + m * 16 + lg * 4 + j;
        if (row < M) C[(size_t)row * Ncols + col] = acc[m][n][j];
        pel[m][j] = fmaf(acc[m][n][j], alw[n], pel[m][j]);
        per_[m][j] = fmaf(acc[m][n][j], arw[n], per_[m][j]);
      }
    }
  }
#pragma unroll
  for (int m = 0; m < 4; ++m) {
#pragma unroll
    for (int j = 0; j < 4; ++j) {
      float vl = pel[m][j], vr = per_[m][j];
#pragma unroll
      for (int off = 1; off < 16; off <<= 1) {
        vl += __shfl_xor(vl, off);
        vr += __shfl_xor(vr, off);
      }
      if (l15 == 0) {
        const int row = row0 + wm * 64 + m * 16 + lg * 4 + j;
        if (row < M) {
          atomicAdd(&el[(size_t)row * Hn + hw], vl);
          atomicAdd(&er[(size_t)row * Hn + hw], vr);
        }
      }
    }
  }
}

// ---------------- CSR build ----------------
__global__ void hist_kernel(const int* __restrict__ dst, int* __restrict__ deg, int E) {
  int i = blockIdx.x * blockDim.x + threadIdx.x;
  if (i < E) atomicAdd(&deg[dst[i]], 1);
}

__global__ void scan1(const int* __restrict__ deg, int* __restrict__ offs,
                      int* __restrict__ bsums, int N) {
  __shared__ int tmp[256];
  const int tid = threadIdx.x;
  const int i = blockIdx.x * 256 + tid;
  int v = (i < N) ? deg[i] : 0;
  tmp[tid] = v;
  __syncthreads();
  for (int d = 1; d < 256; d <<= 1) {
    int t = (tid >= d) ? tmp[tid - d] : 0;
    __syncthreads();
    tmp[tid] += t;
    __syncthreads();
  }
  if (i < N) offs[i] = tmp[tid] - v;
  if (tid == 255) bsums[blockIdx.x] = tmp[255];
}

__global__ void scan2(int* __restrict__ bsums, int nb) {
  __shared__ int tmp[256];
  const int tid = threadIdx.x;
  int v = (tid < nb) ? bsums[tid] : 0;
  tmp[tid] = v;
  __syncthreads();
  for (int d = 1; d < 256; d <<= 1) {
    int t = (tid >= d) ? tmp[tid - d] : 0;
    __syncthreads();
    tmp[tid] += t;
    __syncthreads();
  }
  if (tid < nb) bsums[tid] = tmp[tid] - v;
}

__global__ void scan3(int* __restrict__ offs, const int* __restrict__ bsums, int N, int E) {
  const int i = blockIdx.x * 256 + threadIdx.x;
  if (i < N) offs[i] += bsums[blockIdx.x];
  if (i == 0) offs[N] = E;
}

__global__ void scatter_kernel(const int* __restrict__ src, const int* __restrict__ dst,
                               const int* __restrict__ offs, int* __restrict__ cursor,
                               int* __restrict__ csr_src, int E) {
  int i = blockIdx.x * blockDim.x + threadIdx.x;
  if (i >= E) return;
  int dn = dst[i];
  int pos = atomicAdd(&cursor[dn], 1);
  csr_src[offs[dn] + pos] = src[i];
}

// ---------------- alpha: 16-lane group per dst node (4 nodes/wave) ----------------
template <int H>
__global__ void alpha16(const int* __restrict__ offs, const int* __restrict__ csr_src,
                        const float* __restrict__ el, const float* __restrict__ er,
                        float* __restrict__ abuf, int N) {
  const int w = (int)((blockIdx.x * (size_t)blockDim.x + threadIdx.x) >> 6);
  const int lane = threadIdx.x & 63;
  const int g = lane >> 4, q = lane & 15;
  const int node = w * 4 + g;
  int beg = 0, end = 0;
  float erh[H];
#pragma unroll
  for (int h = 0; h < H; ++h) erh[h] = 0.f;
  if (node < N) {
    beg = offs[node]; end = offs[node + 1];
    if constexpr (H == 4) {
      float4 t = *reinterpret_cast<const float4*>(&er[(size_t)node * 4]);
      erh[0] = t.x; erh[1] = t.y; erh[2] = t.z; erh[3] = t.w;
    } else {
      erh[0] = er[node];
    }
  }
  float m[H], s[H];
#pragma unroll
  for (int h = 0; h < H; ++h) { m[h] = -INFINITY; s[h] = 0.f; }
  for (int i0 = beg; i0 < end; i0 += 16) {
    const int i = i0 + q;
    const bool valid = i < end;
    const int sn = valid ? csr_src[i] : 0;
    float e[H];
    if constexpr (H == 4) {
      float4 v = *reinterpret_cast<const float4*>(&el[(size_t)sn * 4]);
      e[0] = v.x + erh[0]; e[1] = v.y + erh[1]; e[2] = v.z + erh[2]; e[3] = v.w + erh[3];
    } else {
      e[0] = el[sn] + erh[0];
    }
#pragma unroll
    for (int h = 0; h < H; ++h) {
      e[h] = e[h] > 0.f ? e[h] : NEG_SLOPE * e[h];
      if (!valid) e[h] = -INFINITY;
      float cm = e[h];
#pragma unroll
      for (int off = 1; off < 16; off <<= 1) cm = fmaxf(cm, __shfl_xor(cm, off));
      const float nm = fmaxf(m[h], cm);
      float cs = __expf(e[h] - nm);
#pragma unroll
      for (int off = 1; off < 16; off <<= 1) cs += __shfl_xor(cs, off);
      s[h] = s[h] * __expf(m[h] - nm) + cs;
      m[h] = nm;
    }
  }
  float inv[H];
#pragma unroll
  for (int h = 0; h < H; ++h) inv[h] = 1.f / fmaxf(s[h], 1e-9f);
  for (int i0 = beg; i0 < end; i0 += 16) {
    const int i = i0 + q;
    if (i < end) {
      const int sn = csr_src[i];
      float e[H];
      if constexpr (H == 4) {
        float4 v = *reinterpret_cast<const float4*>(&el[(size_t)sn * 4]);
        e[0] = v.x + erh[0]; e[1] = v.y + erh[1]; e[2] = v.z + erh[2]; e[3] = v.w + erh[3];
      } else {
        e[0] = el[sn] + erh[0];
      }
#pragma unroll
      for (int h = 0; h < H; ++h) {
        e[h] = e[h] > 0.f ? e[h] : NEG_SLOPE * e[h];
        e[h] = __expf(e[h] - m[h]) * inv[h];
      }
      if constexpr (H == 4) {
        float4 o; o.x = e[0]; o.y = e[1]; o.z = e[2]; o.w = e[3];
        *reinterpret_cast<float4*>(&abuf[(size_t)i * 4]) = o;
      } else {
        abuf[i] = e[0];
      }
    }
  }
}

// ---------------- aggregate H=4: one wave/node, dwordx4 gather, 4-edge unroll ----------------
template <bool SPLIT>
__global__ void aggregate4(const int* __restrict__ offs, const int* __restrict__ csr_src,
                           const float* __restrict__ feat, const float4* __restrict__ abuf,
                           const float* __restrict__ bias, float* __restrict__ outf,
                           unsigned short* __restrict__ outhi, unsigned short* __restrict__ outlo,
                           int N) {
  const int wid = (int)((blockIdx.x * (size_t)blockDim.x + threadIdx.x) >> 6);
  const int lane = threadIdx.x & 63;
  if (wid >= N) return;
  const int beg = offs[wid], end = offs[wid + 1];
  const int hsel = lane >> 4;
  float4 acc = make_float4(0.f, 0.f, 0.f, 0.f);
  int i = beg;
  for (; i + 3 < end; i += 4) {
    const int s0 = csr_src[i], s1 = csr_src[i + 1], s2 = csr_src[i + 2], s3 = csr_src[i + 3];
    const float4 a0 = abuf[i], a1 = abuf[i + 1], a2 = abuf[i + 2], a3 = abuf[i + 3];
    const float4 v0 = *reinterpret_cast<const float4*>(&feat[(size_t)s0 * 256 + lane * 4]);
    const float4 v1 = *reinterpret_cast<const float4*>(&feat[(size_t)s1 * 256 + lane * 4]);
    const float4 v2 = *reinterpret_cast<const float4*>(&feat[(size_t)s2 * 256 + lane * 4]);
    const float4 v3 = *reinterpret_cast<const float4*>(&feat[(size_t)s3 * 256 + lane * 4]);
    fma4(acc, sel4(a0, hsel), v0);
    fma4(acc, sel4(a1, hsel), v1);
    fma4(acc, sel4(a2, hsel), v2);
    fma4(acc, sel4(a3, hsel), v3);
  }
  for (; i < end; ++i) {
    const int sn = csr_src[i];
    const float4 a = abuf[i];
    const float4 v = *reinterpret_cast<const float4*>(&feat[(size_t)sn * 256 + lane * 4]);
    fma4(acc, sel4(a, hsel), v);
  }
  const float4 b4 = *reinterpret_cast<const float4*>(&bias[lane * 4]);
  const float4 o = make_float4(acc.x + b4.x, acc.y + b4.y, acc.z + b4.z, acc.w + b4.w);
  const size_t idx = (size_t)wid * 256 + lane * 4;
  if constexpr (SPLIT) {
    ushort4 hv, lv;
    hv.x = f2bf(o.x); lv.x = f2bf(o.x - bf2f(hv.x));
    hv.y = f2bf(o.y); lv.y = f2bf(o.y - bf2f(hv.y));
    hv.z = f2bf(o.z); lv.z = f2bf(o.z - bf2f(hv.z));
    hv.w = f2bf(o.w); lv.w = f2bf(o.w - bf2f(hv.w));
    *reinterpret_cast<ushort4*>(&outhi[idx]) = hv;
    *reinterpret_cast<ushort4*>(&outlo[idx]) = lv;
  } else {
    *reinterpret_cast<float4*>(&outf[idx]) = o;
  }
}

// ---------------- aggregate H=1: 16-lane groups, 4 edges/iter ----------------
__global__ void aggregate1(const int* __restrict__ offs, const int* __restrict__ csr_src,
                           const float* __restrict__ feat, const float* __restrict__ abuf,
                           const float* __restrict__ bias, float* __restrict__ outf, int N) {
  const int wid = (int)((blockIdx.x * (size_t)blockDim.x + threadIdx.x) >> 6);
  const int lane = threadIdx.x & 63;
  if (wid >= N) return;
  const int beg = offs[wid], end = offs[wid + 1];
  const int g = lane >> 4, q = lane & 15;
  float4 acc = make_float4(0.f, 0.f, 0.f, 0.f);
  for (int i0 = beg; i0 < end; i0 += 4) {
    const int e = i0 + g;
    if (e < end) {
      const int sn = csr_src[e];
      const float a = abuf[e];
      const float4 v = *reinterpret_cast<const float4*>(&feat[(size_t)sn * 64 + q * 4]);
      fma4(acc, a, v);
    }
  }
#pragma unroll
  for (int off = 16; off <= 32; off <<= 1) {
    acc.x += __shfl_xor(acc.x, off);
    acc.y += __shfl_xor(acc.y, off);
    acc.z += __shfl_xor(acc.z, off);
    acc.w += __shfl_xor(acc.w, off);
  }
  if (lane < 16) {
    const float4 b4 = *reinterpret_cast<const float4*>(&bias[q * 4]);
    float4 o = make_float4(acc.x + b4.x, acc.y + b4.y, acc.z + b4.z, acc.w + b4.w);
    *reinterpret_cast<float4*>(&outf[(size_t)wid * 64 + q * 4]) = o;
  }
}

// ---------------- tail: ids as float ----------------
__global__ void copy_ids(const int* __restrict__ ids, float* __restrict__ out, int n) {
  int i = blockIdx.x * blockDim.x + threadIdx.x;
  if (i < n) out[i] = (float)ids[i];
}

extern "C" void kernel_launch(void* const* d_in, const int* in_sizes, int n_in,
                              void* d_out, int out_size, void* d_ws, size_t ws_size,
                              hipStream_t stream) {
  const float* h   = (const float*)d_in[0];
  const int* src   = (const int*)d_in[1];
  const int* dst   = (const int*)d_in[2];
  const int* ids   = (const int*)d_in[3];
  const float* W0  = (const float*)d_in[4];
  const float* al0 = (const float*)d_in[5];
  const float* ar0 = (const float*)d_in[6];
  const float* b0  = (const float*)d_in[7];
  const float* W1  = (const float*)d_in[8];
  const float* al1 = (const float*)d_in[9];
  const float* ar1 = (const float*)d_in[10];
  const float* b1  = (const float*)d_in[11];
  const float* W2  = (const float*)d_in[12];
  const float* al2 = (const float*)d_in[13];
  const float* ar2 = (const float*)d_in[14];
  const float* b2  = (const float*)d_in[15];

  const int Din = 256, HF = 256, F2 = 64;
  const int N = in_sizes[0] / Din;        // 50000
  const int E = in_sizes[1];              // 800000
  const int NIDS = in_sizes[3];           // 1024

  // workspace layout (16B-aligned chunks)
  char* p = (char*)d_ws;
  float* feat = (float*)p;             p += (size_t)N * 256 * 4;
  unsigned short* Ahi = (unsigned short*)p; p += (size_t)N * 256 * 2;
  unsigned short* Alo = (unsigned short*)p; p += (size_t)N * 256 * 2;
  unsigned short* W0hi = (unsigned short*)p; p += (size_t)HF * Din * 2;
  unsigned short* W0lo = (unsigned short*)p; p += (size_t)HF * Din * 2;
  unsigned short* W1hi = (unsigned short*)p; p += (size_t)HF * HF * 2;
  unsigned short* W1lo = (unsigned short*)p; p += (size_t)HF * HF * 2;
  unsigned short* W2hi = (unsigned short*)p; p += (size_t)F2 * HF * 2;
  unsigned short* W2lo = (unsigned short*)p; p += (size_t)F2 * HF * 2;
  float* el   = (float*)p;             p += (size_t)N * 4 * 4;
  float* er   = (float*)p;             p += (size_t)N * 4 * 4;
  float* abuf = (float*)p;             p += (size_t)E * 4 * 4;
  int* deg    = (int*)p;               p += (size_t)N * 4;
  int* offs   = (int*)p;               p += (size_t)(N + 16) * 4;
  int* bsums  = (int*)p;               p += 256 * 4;
  int* csr_src = (int*)p;              p += (size_t)E * 4;

  float* outp = (float*)d_out;
  dim3 blk(256);
  const int nb = cdiv(N, 256);
  const int nwAlpha = cdiv(cdiv(N, 4) * 64, 256);

  // ---------------- pre-passes: splits ----------------
  split_kernel<<<cdiv(N * 256 / 4, 256), blk, 0, stream>>>(h, Ahi, Alo, N * 256 / 4);
  splitT_kernel<<<cdiv(Din * HF, 256), blk, 0, stream>>>(W0, W0hi, W0lo, Din, HF);
  splitT_kernel<<<cdiv(HF * HF, 256), blk, 0, stream>>>(W1, W1hi, W1lo, HF, HF);
  splitT_kernel<<<cdiv(HF * F2, 256), blk, 0, stream>>>(W2, W2hi, W2lo, HF, F2);

  // ---------------- CSR build (shared by all 3 layers) ----------------
  hipMemsetAsync(deg, 0, (size_t)N * 4, stream);
  hist_kernel<<<cdiv(E, 256), blk, 0, stream>>>(dst, deg, E);
  scan1<<<nb, blk, 0, stream>>>(deg, offs, bsums, N);
  scan2<<<1, blk, 0, stream>>>(bsums, nb);
  scan3<<<nb, blk, 0, stream>>>(offs, bsums, N, E);
  hipMemsetAsync(deg, 0, (size_t)N * 4, stream);
  scatter_kernel<<<cdiv(E, 256), blk, 0, stream>>>(src, dst, offs, deg, csr_src, E);

  // ---------------- layer 0 (H=4): (Ahi,Alo) -> feat -> (Ahi,Alo) ----------------
  {
    hipMemsetAsync(el, 0, (size_t)N * 4 * 4 * 2, stream);   // el+er contiguous
    dim3 g(cdiv(N, 128), HF / 128);
    gemm_split<4><<<g, blk, 0, stream>>>(Ahi, Alo, W0hi, W0lo, feat, al0, ar0, el, er, 4, N, Din, HF);
    alpha16<4><<<nwAlpha, blk, 0, stream>>>(offs, csr_src, el, er, abuf, N);
    aggregate4<true><<<cdiv(N * 64, 256), blk, 0, stream>>>(offs, csr_src, feat, (const float4*)abuf,
                                                            b0, nullptr, Ahi, Alo, N);
  }
  // ---------------- layer 1 (H=4) ----------------
  {
    hipMemsetAsync(el, 0, (size_t)N * 4 * 4 * 2, stream);
    dim3 g(cdiv(N, 128), HF / 128);
    gemm_split<4><<<g, blk, 0, stream>>>(Ahi, Alo, W1hi, W1lo, feat, al1, ar1, el, er, 4, N, HF, HF);
    alpha16<4><<<nwAlpha, blk, 0, stream>>>(offs, csr_src, el, er, abuf, N);
    aggregate4<true><<<cdiv(N * 64, 256), blk, 0, stream>>>(offs, csr_src, feat, (const float4*)abuf,
                                                            b1, nullptr, Ahi, Alo, N);
  }
  // ---------------- layer 2 (H=1): -> d_out ----------------
  {
    hipMemsetAsync(el, 0, (size_t)N * 4 * 4 * 2, stream);
    dim3 g(cdiv(N, 128), 1);
    gemm_split<2><<<g, blk, 0, stream>>>(Ahi, Alo, W2hi, W2lo, feat, al2, ar2, el, er, 1, N, HF, F2);
    alpha16<1><<<nwAlpha, blk, 0, stream>>>(offs, csr_src, el, er, abuf, N);
    aggregate1<<<cdiv(N * 64, 256), blk, 0, stream>>>(offs, csr_src, feat, abuf, b2, outp, N);
  }
  // ---------------- tail ids ----------------
  copy_ids<<<cdiv(NIDS, 256), blk, 0, stream>>>(ids, outp + (size_t)N * F2, NIDS);
}

// Round 5
// 473.674 us; speedup vs baseline: 1.3340x; 1.3340x over previous
//
#include <hip/hip_runtime.h>
#include <hip/hip_bf16.h>

#define NEG_SLOPE 0.2f

typedef __attribute__((ext_vector_type(8))) short bf16x8;
typedef __attribute__((ext_vector_type(4))) float f32x4;

static inline int cdiv(int a, int b) { return (a + b - 1) / b; }

__device__ inline unsigned short f2bf(float x) {
  __hip_bfloat16 b = __float2bfloat16(x);
  return *reinterpret_cast<unsigned short*>(&b);
}
__device__ inline float bf2f(unsigned short u) {
  unsigned int v = (unsigned int)u << 16;
  return *reinterpret_cast<float*>(&v);
}

// ---------------- split f32 -> bf16 hi/lo ----------------
__global__ void split_kernel(const float* __restrict__ x, unsigned short* __restrict__ hi,
                             unsigned short* __restrict__ lo, int n4) {
  int i = blockIdx.x * blockDim.x + threadIdx.x;
  if (i >= n4) return;
  float4 v = reinterpret_cast<const float4*>(x)[i];
  unsigned short h0 = f2bf(v.x), h1 = f2bf(v.y), h2 = f2bf(v.z), h3 = f2bf(v.w);
  ushort4 hv; hv.x = h0; hv.y = h1; hv.z = h2; hv.w = h3;
  ushort4 lv;
  lv.x = f2bf(v.x - bf2f(h0)); lv.y = f2bf(v.y - bf2f(h1));
  lv.z = f2bf(v.z - bf2f(h2)); lv.w = f2bf(v.w - bf2f(h3));
  reinterpret_cast<ushort4*>(hi)[i] = hv;
  reinterpret_cast<ushort4*>(lo)[i] = lv;
}

// ---------------- split + transpose W[K][Mo] -> T[Mo][K] bf16 hi/lo ----------------
__global__ void splitT_kernel(const float* __restrict__ W, unsigned short* __restrict__ hi,
                              unsigned short* __restrict__ lo, int K, int Mo) {
  int i = blockIdx.x * blockDim.x + threadIdx.x;
  if (i >= K * Mo) return;
  int k = i / Mo, m = i - k * Mo;
  float v = W[i];
  unsigned short h = f2bf(v);
  hi[(size_t)m * K + k] = h;
  lo[(size_t)m * K + k] = f2bf(v - bf2f(h));
}

// ---------------- GEMM + fused attention-score partials; C written as bf16 hi/lo ----------------
// (Chi+Clo)[M][Ncols] = (Ahi+Alo)[M][K] @ (BThi+BTlo)[Ncols][K]^T ; el/er += C·al / C·ar (atomic)
template <int NF>
__global__ __launch_bounds__(256) void gemm_split(
    const unsigned short* __restrict__ Ahi, const unsigned short* __restrict__ Alo,
    const unsigned short* __restrict__ BThi, const unsigned short* __restrict__ BTlo,
    unsigned short* __restrict__ Chi, unsigned short* __restrict__ Clo,
    const float* __restrict__ alv, const float* __restrict__ arv,
    float* __restrict__ el, float* __restrict__ er, int Hn, int M, int K, int Ncols) {
  constexpr int BN = NF * 32;
  __shared__ unsigned short As[128][88];   // hi at [0,32), lo at [48,80)
  __shared__ unsigned short Bs[BN][88];
  const int tid = threadIdx.x;
  const int row0 = blockIdx.x * 128;
  const int col0 = blockIdx.y * BN;
  const int wid = tid >> 6, lane = tid & 63;
  const int wm = wid >> 1, wn = wid & 1;
  const int l15 = lane & 15, lg = lane >> 4;
  f32x4 acc[4][NF];
#pragma unroll
  for (int m = 0; m < 4; ++m)
#pragma unroll
    for (int n = 0; n < NF; ++n) acc[m][n] = (f32x4){0.f, 0.f, 0.f, 0.f};

  const uint4 zero4 = {0u, 0u, 0u, 0u};
  for (int k0 = 0; k0 < K; k0 += 32) {
    {
      int r = tid >> 2;
      const int kg = tid & 3;
#pragma unroll
      for (int it = 0; it < 2; ++it, r += 64) {
        const int grow = row0 + r;
        uint4 vh = zero4, vl = zero4;
        if (grow < M) {
          vh = *reinterpret_cast<const uint4*>(&Ahi[(size_t)grow * K + k0 + kg * 8]);
          vl = *reinterpret_cast<const uint4*>(&Alo[(size_t)grow * K + k0 + kg * 8]);
        }
        *reinterpret_cast<uint4*>(&As[r][kg * 8]) = vh;
        *reinterpret_cast<uint4*>(&As[r][48 + kg * 8]) = vl;
      }
    }
    {
      int r = tid >> 2;
      const int kg = tid & 3;
#pragma unroll
      for (int it = 0; it < BN / 64; ++it, r += 64) {
        const int gcol = col0 + r;
        uint4 vh = *reinterpret_cast<const uint4*>(&BThi[(size_t)gcol * K + k0 + kg * 8]);
        uint4 vl = *reinterpret_cast<const uint4*>(&BTlo[(size_t)gcol * K + k0 + kg * 8]);
        *reinterpret_cast<uint4*>(&Bs[r][kg * 8]) = vh;
        *reinterpret_cast<uint4*>(&Bs[r][48 + kg * 8]) = vl;
      }
    }
    __syncthreads();
    bf16x8 ah[4], al[4];
#pragma unroll
    for (int m = 0; m < 4; ++m) {
      const int row = wm * 64 + m * 16 + l15;
      ah[m] = *reinterpret_cast<const bf16x8*>(&As[row][lg * 8]);
      al[m] = *reinterpret_cast<const bf16x8*>(&As[row][48 + lg * 8]);
    }
#pragma unroll
    for (int n = 0; n < NF; ++n) {
      const int col = wn * (NF * 16) + n * 16 + l15;
      bf16x8 bh = *reinterpret_cast<const bf16x8*>(&Bs[col][lg * 8]);
      bf16x8 bl = *reinterpret_cast<const bf16x8*>(&Bs[col][48 + lg * 8]);
#pragma unroll
      for (int m = 0; m < 4; ++m) {
        acc[m][n] = __builtin_amdgcn_mfma_f32_16x16x32_bf16(ah[m], bh, acc[m][n], 0, 0, 0);
        acc[m][n] = __builtin_amdgcn_mfma_f32_16x16x32_bf16(ah[m], bl, acc[m][n], 0, 0, 0);
        acc[m][n] = __builtin_amdgcn_mfma_f32_16x16x32_bf16(al[m], bh, acc[m][n], 0, 0, 0);
      }
    }
    __syncthreads();
  }
  // wave's NF col-frags all lie in one head (NF*16 <= 64)
  const int hw = (col0 + wn * (NF * 16)) >> 6;
  float alw[NF], arw[NF];
#pragma unroll
  for (int n = 0; n < NF; ++n) {
    const int colg = col0 + wn * (NF * 16) + n * 16 + l15;
    alw[n] = alv[colg];
    arw[n] = arv[colg];
  }
  float pel[4][4] = {{0.f}}, per_[4][4] = {{0.f}};
  // epilogue: C/D layout col=lane&15, row=(lane>>4)*4+j
#pragma unroll
  for (int m = 0; m < 4; ++m) {
#pragma unroll
    for (int n = 0; n < NF; ++n) {
      const int col = col0 + wn * (NF * 16) + n * 16 + l15;
#pragma unroll
      for (int j = 0; j < 4; ++j) {
        const int row = row0 + wm * 64 + m * 16 + lg * 4 + j;
        const float v = acc[m][n][j];
        if (row < M) {
          const unsigned short hb = f2bf(v);
          Chi[(size_t)row * Ncols + col] = hb;
          Clo[(size_t)row * Ncols + col] = f2bf(v - bf2f(hb));
        }
        pel[m][j] = fmaf(v, alw[n], pel[m][j]);
        per_[m][j] = fmaf(v, arw[n], per_[m][j]);
      }
    }
  }
#pragma unroll
  for (int m = 0; m < 4; ++m) {
#pragma unroll
    for (int j = 0; j < 4; ++j) {
      float vl = pel[m][j], vr = per_[m][j];
#pragma unroll
      for (int off = 1; off < 16; off <<= 1) {
        vl += __shfl_xor(vl, off);
        vr += __shfl_xor(vr, off);
      }
      if (l15 == 0) {
        const int row = row0 + wm * 64 + m * 16 + lg * 4 + j;
        if (row < M) {
          atomicAdd(&el[(size_t)row * Hn + hw], vl);
          atomicAdd(&er[(size_t)row * Hn + hw], vr);
        }
      }
    }
  }
}

// ---------------- CSR build ----------------
__global__ void hist_kernel(const int* __restrict__ dst, int* __restrict__ deg, int E) {
  int i = blockIdx.x * blockDim.x + threadIdx.x;
  if (i < E) atomicAdd(&deg[dst[i]], 1);
}

__global__ void scan1(const int* __restrict__ deg, int* __restrict__ offs,
                      int* __restrict__ bsums, int N) {
  __shared__ int tmp[256];
  const int tid = threadIdx.x;
  const int i = blockIdx.x * 256 + tid;
  int v = (i < N) ? deg[i] : 0;
  tmp[tid] = v;
  __syncthreads();
  for (int d = 1; d < 256; d <<= 1) {
    int t = (tid >= d) ? tmp[tid - d] : 0;
    __syncthreads();
    tmp[tid] += t;
    __syncthreads();
  }
  if (i < N) offs[i] = tmp[tid] - v;
  if (tid == 255) bsums[blockIdx.x] = tmp[255];
}

__global__ void scan2(int* __restrict__ bsums, int nb) {
  __shared__ int tmp[256];
  const int tid = threadIdx.x;
  int v = (tid < nb) ? bsums[tid] : 0;
  tmp[tid] = v;
  __syncthreads();
  for (int d = 1; d < 256; d <<= 1) {
    int t = (tid >= d) ? tmp[tid - d] : 0;
    __syncthreads();
    tmp[tid] += t;
    __syncthreads();
  }
  if (tid < nb) bsums[tid] = tmp[tid] - v;
}

__global__ void scan3(int* __restrict__ offs, const int* __restrict__ bsums, int N, int E) {
  const int i = blockIdx.x * 256 + threadIdx.x;
  if (i < N) offs[i] += bsums[blockIdx.x];
  if (i == 0) offs[N] = E;
}

__global__ void scatter_kernel(const int* __restrict__ src, const int* __restrict__ dst,
                               const int* __restrict__ offs, int* __restrict__ cursor,
                               int* __restrict__ csr_src, int E) {
  int i = blockIdx.x * blockDim.x + threadIdx.x;
  if (i >= E) return;
  int dn = dst[i];
  int pos = atomicAdd(&cursor[dn], 1);
  csr_src[offs[dn] + pos] = src[i];
}

// ---------------- alpha: 16-lane group per dst node (4 nodes/wave) ----------------
template <int H>
__global__ void alpha16(const int* __restrict__ offs, const int* __restrict__ csr_src,
                        const float* __restrict__ el, const float* __restrict__ er,
                        float* __restrict__ abuf, int N) {
  const int w = (int)((blockIdx.x * (size_t)blockDim.x + threadIdx.x) >> 6);
  const int lane = threadIdx.x & 63;
  const int g = lane >> 4, q = lane & 15;
  const int node = w * 4 + g;
  int beg = 0, end = 0;
  float erh[H];
#pragma unroll
  for (int h = 0; h < H; ++h) erh[h] = 0.f;
  if (node < N) {
    beg = offs[node]; end = offs[node + 1];
    if constexpr (H == 4) {
      float4 t = *reinterpret_cast<const float4*>(&er[(size_t)node * 4]);
      erh[0] = t.x; erh[1] = t.y; erh[2] = t.z; erh[3] = t.w;
    } else {
      erh[0] = er[node];
    }
  }
  float m[H], s[H];
#pragma unroll
  for (int h = 0; h < H; ++h) { m[h] = -INFINITY; s[h] = 0.f; }
  for (int i0 = beg; i0 < end; i0 += 16) {
    const int i = i0 + q;
    const bool valid = i < end;
    const int sn = valid ? csr_src[i] : 0;
    float e[H];
    if constexpr (H == 4) {
      float4 v = *reinterpret_cast<const float4*>(&el[(size_t)sn * 4]);
      e[0] = v.x + erh[0]; e[1] = v.y + erh[1]; e[2] = v.z + erh[2]; e[3] = v.w + erh[3];
    } else {
      e[0] = el[sn] + erh[0];
    }
#pragma unroll
    for (int h = 0; h < H; ++h) {
      e[h] = e[h] > 0.f ? e[h] : NEG_SLOPE * e[h];
      if (!valid) e[h] = -INFINITY;
      float cm = e[h];
#pragma unroll
      for (int off = 1; off < 16; off <<= 1) cm = fmaxf(cm, __shfl_xor(cm, off));
      const float nm = fmaxf(m[h], cm);
      float cs = __expf(e[h] - nm);
#pragma unroll
      for (int off = 1; off < 16; off <<= 1) cs += __shfl_xor(cs, off);
      s[h] = s[h] * __expf(m[h] - nm) + cs;
      m[h] = nm;
    }
  }
  float inv[H];
#pragma unroll
  for (int h = 0; h < H; ++h) inv[h] = 1.f / fmaxf(s[h], 1e-9f);
  for (int i0 = beg; i0 < end; i0 += 16) {
    const int i = i0 + q;
    if (i < end) {
      const int sn = csr_src[i];
      float e[H];
      if constexpr (H == 4) {
        float4 v = *reinterpret_cast<const float4*>(&el[(size_t)sn * 4]);
        e[0] = v.x + erh[0]; e[1] = v.y + erh[1]; e[2] = v.z + erh[2]; e[3] = v.w + erh[3];
      } else {
        e[0] = el[sn] + erh[0];
      }
#pragma unroll
      for (int h = 0; h < H; ++h) {
        e[h] = e[h] > 0.f ? e[h] : NEG_SLOPE * e[h];
        e[h] = __expf(e[h] - m[h]) * inv[h];
      }
      if constexpr (H == 4) {
        float4 o; o.x = e[0]; o.y = e[1]; o.z = e[2]; o.w = e[3];
        *reinterpret_cast<float4*>(&abuf[(size_t)i * 4]) = o;
      } else {
        abuf[i] = e[0];
      }
    }
  }
}

// ---------------- aggregate H=4: one wave/node, bf16 gather (R3-proven shape), 4-edge unroll ----------------
// lane owns feature (h*64 + lane) for h=0..3; reads Chi only (hi bf16 of feat)
template <bool SPLIT>
__global__ void aggregate_h4(const int* __restrict__ offs, const int* __restrict__ csr_src,
                             const unsigned short* __restrict__ featH, const float4* __restrict__ abuf,
                             const float* __restrict__ bias, float* __restrict__ outf,
                             unsigned short* __restrict__ outhi, unsigned short* __restrict__ outlo,
                             int N) {
  const int wid = (int)((blockIdx.x * (size_t)blockDim.x + threadIdx.x) >> 6);
  const int lane = threadIdx.x & 63;
  if (wid >= N) return;
  const int beg = offs[wid], end = offs[wid + 1];
  float a0 = 0.f, a1 = 0.f, a2 = 0.f, a3 = 0.f;
  int i = beg;
  for (; i + 3 < end; i += 4) {
    const int s0 = csr_src[i], s1 = csr_src[i + 1], s2 = csr_src[i + 2], s3 = csr_src[i + 3];
    const float4 w0 = abuf[i], w1 = abuf[i + 1], w2 = abuf[i + 2], w3 = abuf[i + 3];
    const unsigned short* f0 = &featH[(size_t)s0 * 256 + lane];
    const unsigned short* f1 = &featH[(size_t)s1 * 256 + lane];
    const unsigned short* f2 = &featH[(size_t)s2 * 256 + lane];
    const unsigned short* f3 = &featH[(size_t)s3 * 256 + lane];
    const unsigned short u00 = f0[0], u01 = f0[64], u02 = f0[128], u03 = f0[192];
    const unsigned short u10 = f1[0], u11 = f1[64], u12 = f1[128], u13 = f1[192];
    const unsigned short u20 = f2[0], u21 = f2[64], u22 = f2[128], u23 = f2[192];
    const unsigned short u30 = f3[0], u31 = f3[64], u32 = f3[128], u33 = f3[192];
    a0 += w0.x * bf2f(u00) + w1.x * bf2f(u10) + w2.x * bf2f(u20) + w3.x * bf2f(u30);
    a1 += w0.y * bf2f(u01) + w1.y * bf2f(u11) + w2.y * bf2f(u21) + w3.y * bf2f(u31);
    a2 += w0.z * bf2f(u02) + w1.z * bf2f(u12) + w2.z * bf2f(u22) + w3.z * bf2f(u32);
    a3 += w0.w * bf2f(u03) + w1.w * bf2f(u13) + w2.w * bf2f(u23) + w3.w * bf2f(u33);
  }
  for (; i < end; ++i) {
    const int sn = csr_src[i];
    const float4 w = abuf[i];
    const unsigned short* f = &featH[(size_t)sn * 256 + lane];
    a0 += w.x * bf2f(f[0]);
    a1 += w.y * bf2f(f[64]);
    a2 += w.z * bf2f(f[128]);
    a3 += w.w * bf2f(f[192]);
  }
  const float o0 = a0 + bias[lane];
  const float o1 = a1 + bias[64 + lane];
  const float o2 = a2 + bias[128 + lane];
  const float o3 = a3 + bias[192 + lane];
  const size_t base = (size_t)wid * 256 + lane;
  if constexpr (SPLIT) {
    unsigned short hb;
    hb = f2bf(o0); outhi[base] = hb;       outlo[base] = f2bf(o0 - bf2f(hb));
    hb = f2bf(o1); outhi[base + 64] = hb;  outlo[base + 64] = f2bf(o1 - bf2f(hb));
    hb = f2bf(o2); outhi[base + 128] = hb; outlo[base + 128] = f2bf(o2 - bf2f(hb));
    hb = f2bf(o3); outhi[base + 192] = hb; outlo[base + 192] = f2bf(o3 - bf2f(hb));
  } else {
    outf[base] = o0; outf[base + 64] = o1; outf[base + 128] = o2; outf[base + 192] = o3;
  }
}

// ---------------- aggregate H=1: 16-lane groups, 4 edges/iter, bf16 gather ----------------
__global__ void aggregate1(const int* __restrict__ offs, const int* __restrict__ csr_src,
                           const unsigned short* __restrict__ featH, const float* __restrict__ abuf,
                           const float* __restrict__ bias, float* __restrict__ outf, int N) {
  const int wid = (int)((blockIdx.x * (size_t)blockDim.x + threadIdx.x) >> 6);
  const int lane = threadIdx.x & 63;
  if (wid >= N) return;
  const int beg = offs[wid], end = offs[wid + 1];
  const int g = lane >> 4, q = lane & 15;
  float4 acc = make_float4(0.f, 0.f, 0.f, 0.f);
  for (int i0 = beg; i0 < end; i0 += 4) {
    const int e = i0 + g;
    if (e < end) {
      const int sn = csr_src[e];
      const float a = abuf[e];
      const ushort4 u = *reinterpret_cast<const ushort4*>(&featH[(size_t)sn * 64 + q * 4]);
      acc.x = fmaf(a, bf2f(u.x), acc.x);
      acc.y = fmaf(a, bf2f(u.y), acc.y);
      acc.z = fmaf(a, bf2f(u.z), acc.z);
      acc.w = fmaf(a, bf2f(u.w), acc.w);
    }
  }
#pragma unroll
  for (int off = 16; off <= 32; off <<= 1) {
    acc.x += __shfl_xor(acc.x, off);
    acc.y += __shfl_xor(acc.y, off);
    acc.z += __shfl_xor(acc.z, off);
    acc.w += __shfl_xor(acc.w, off);
  }
  if (lane < 16) {
    const float4 b4 = *reinterpret_cast<const float4*>(&bias[q * 4]);
    float4 o = make_float4(acc.x + b4.x, acc.y + b4.y, acc.z + b4.z, acc.w + b4.w);
    *reinterpret_cast<float4*>(&outf[(size_t)wid * 64 + q * 4]) = o;
  }
}

// ---------------- tail: ids as float ----------------
__global__ void copy_ids(const int* __restrict__ ids, float* __restrict__ out, int n) {
  int i = blockIdx.x * blockDim.x + threadIdx.x;
  if (i < n) out[i] = (float)ids[i];
}

extern "C" void kernel_launch(void* const* d_in, const int* in_sizes, int n_in,
                              void* d_out, int out_size, void* d_ws, size_t ws_size,
                              hipStream_t stream) {
  const float* h   = (const float*)d_in[0];
  const int* src   = (const int*)d_in[1];
  const int* dst   = (const int*)d_in[2];
  const int* ids   = (const int*)d_in[3];
  const float* W0  = (const float*)d_in[4];
  const float* al0 = (const float*)d_in[5];
  const float* ar0 = (const float*)d_in[6];
  const float* b0  = (const float*)d_in[7];
  const float* W1  = (const float*)d_in[8];
  const float* al1 = (const float*)d_in[9];
  const float* ar1 = (const float*)d_in[10];
  const float* b1  = (const float*)d_in[11];
  const float* W2  = (const float*)d_in[12];
  const float* al2 = (const float*)d_in[13];
  const float* ar2 = (const float*)d_in[14];
  const float* b2  = (const float*)d_in[15];

  const int Din = 256, HF = 256, F2 = 64;
  const int N = in_sizes[0] / Din;        // 50000
  const int E = in_sizes[1];              // 800000
  const int NIDS = in_sizes[3];           // 1024

  // workspace layout (16B-aligned chunks)
  char* p = (char*)d_ws;
  unsigned short* Chi = (unsigned short*)p; p += (size_t)N * 256 * 2;  // feat bf16 hi
  unsigned short* Clo = (unsigned short*)p; p += (size_t)N * 256 * 2;  // feat bf16 lo
  unsigned short* Ahi = (unsigned short*)p; p += (size_t)N * 256 * 2;  // GEMM input hi
  unsigned short* Alo = (unsigned short*)p; p += (size_t)N * 256 * 2;  // GEMM input lo
  unsigned short* W0hi = (unsigned short*)p; p += (size_t)HF * Din * 2;
  unsigned short* W0lo = (unsigned short*)p; p += (size_t)HF * Din * 2;
  unsigned short* W1hi = (unsigned short*)p; p += (size_t)HF * HF * 2;
  unsigned short* W1lo = (unsigned short*)p; p += (size_t)HF * HF * 2;
  unsigned short* W2hi = (unsigned short*)p; p += (size_t)F2 * HF * 2;
  unsigned short* W2lo = (unsigned short*)p; p += (size_t)F2 * HF * 2;
  float* el   = (float*)p;             p += (size_t)N * 4 * 4;
  float* er   = (float*)p;             p += (size_t)N * 4 * 4;
  float* abuf = (float*)p;             p += (size_t)E * 4 * 4;
  int* deg    = (int*)p;               p += (size_t)N * 4;
  int* offs   = (int*)p;               p += (size_t)(N + 16) * 4;
  int* bsums  = (int*)p;               p += 256 * 4;
  int* csr_src = (int*)p;              p += (size_t)E * 4;

  float* outp = (float*)d_out;
  dim3 blk(256);
  const int nb = cdiv(N, 256);
  const int nwAlpha = cdiv(cdiv(N, 4) * 64, 256);

  // ---------------- pre-passes: splits ----------------
  split_kernel<<<cdiv(N * 256 / 4, 256), blk, 0, stream>>>(h, Ahi, Alo, N * 256 / 4);
  splitT_kernel<<<cdiv(Din * HF, 256), blk, 0, stream>>>(W0, W0hi, W0lo, Din, HF);
  splitT_kernel<<<cdiv(HF * HF, 256), blk, 0, stream>>>(W1, W1hi, W1lo, HF, HF);
  splitT_kernel<<<cdiv(HF * F2, 256), blk, 0, stream>>>(W2, W2hi, W2lo, HF, F2);

  // ---------------- CSR build (shared by all 3 layers) ----------------
  hipMemsetAsync(deg, 0, (size_t)N * 4, stream);
  hist_kernel<<<cdiv(E, 256), blk, 0, stream>>>(dst, deg, E);
  scan1<<<nb, blk, 0, stream>>>(deg, offs, bsums, N);
  scan2<<<1, blk, 0, stream>>>(bsums, nb);
  scan3<<<nb, blk, 0, stream>>>(offs, bsums, N, E);
  hipMemsetAsync(deg, 0, (size_t)N * 4, stream);
  scatter_kernel<<<cdiv(E, 256), blk, 0, stream>>>(src, dst, offs, deg, csr_src, E);

  // ---------------- layer 0 (H=4): (Ahi,Alo) -> (Chi,Clo) -> (Ahi,Alo) ----------------
  {
    hipMemsetAsync(el, 0, (size_t)N * 4 * 4 * 2, stream);   // el+er contiguous
    dim3 g(cdiv(N, 128), HF / 128);
    gemm_split<4><<<g, blk, 0, stream>>>(Ahi, Alo, W0hi, W0lo, Chi, Clo, al0, ar0, el, er, 4, N, Din, HF);
    alpha16<4><<<nwAlpha, blk, 0, stream>>>(offs, csr_src, el, er, abuf, N);
    aggregate_h4<true><<<cdiv(N * 64, 256), blk, 0, stream>>>(offs, csr_src, Chi, (const float4*)abuf,
                                                              b0, nullptr, Ahi, Alo, N);
  }
  // ---------------- layer 1 (H=4) ----------------
  {
    hipMemsetAsync(el, 0, (size_t)N * 4 * 4 * 2, stream);
    dim3 g(cdiv(N, 128), HF / 128);
    gemm_split<4><<<g, blk, 0, stream>>>(Ahi, Alo, W1hi, W1lo, Chi, Clo, al1, ar1, el, er, 4, N, HF, HF);
    alpha16<4><<<nwAlpha, blk, 0, stream>>>(offs, csr_src, el, er, abuf, N);
    aggregate_h4<true><<<cdiv(N * 64, 256), blk, 0, stream>>>(offs, csr_src, Chi, (const float4*)abuf,
                                                              b1, nullptr, Ahi, Alo, N);
  }
  // ---------------- layer 2 (H=1): -> d_out ----------------
  {
    hipMemsetAsync(el, 0, (size_t)N * 4 * 4 * 2, stream);
    dim3 g(cdiv(N, 128), 1);
    gemm_split<2><<<g, blk, 0, stream>>>(Ahi, Alo, W2hi, W2lo, Chi, Clo, al2, ar2, el, er, 1, N, HF, F2);
    alpha16<1><<<nwAlpha, blk, 0, stream>>>(offs, csr_src, el, er, abuf, N);
    aggregate1<<<cdiv(N * 64, 256), blk, 0, stream>>>(offs, csr_src, Chi, abuf, b2, outp, N);
  }
  // ---------------- tail ids ----------------
  copy_ids<<<cdiv(NIDS, 256), blk, 0, stream>>>(ids, outp + (size_t)N * F2, NIDS);
}

// Round 6
// 436.025 us; speedup vs baseline: 1.4492x; 1.0863x over previous
//
#include <hip/hip_runtime.h>
#include <hip/hip_bf16.h>

#define NEG_SLOPE 0.2f

typedef __attribute__((ext_vector_type(8))) short bf16x8;
typedef __attribute__((ext_vector_type(4))) float f32x4;

static inline int cdiv(int a, int b) { return (a + b - 1) / b; }

__device__ inline unsigned short f2bf(float x) {
  __hip_bfloat16 b = __float2bfloat16(x);
  return *reinterpret_cast<unsigned short*>(&b);
}
__device__ inline float bf2f(unsigned short u) {
  unsigned int v = (unsigned int)u << 16;
  return *reinterpret_cast<float*>(&v);
}

// ---------------- h (f32) -> bf16 hi only ----------------
__global__ void split_hi_kernel(const float* __restrict__ x, unsigned short* __restrict__ hi, int n4) {
  int i = blockIdx.x * blockDim.x + threadIdx.x;
  if (i >= n4) return;
  float4 v = reinterpret_cast<const float4*>(x)[i];
  ushort4 hv; hv.x = f2bf(v.x); hv.y = f2bf(v.y); hv.z = f2bf(v.z); hv.w = f2bf(v.w);
  reinterpret_cast<ushort4*>(hi)[i] = hv;
}

// ---------------- split + transpose W[K][Mo] -> T[Mo][K] bf16 hi/lo ----------------
__global__ void splitT_kernel(const float* __restrict__ W, unsigned short* __restrict__ hi,
                              unsigned short* __restrict__ lo, int K, int Mo) {
  int i = blockIdx.x * blockDim.x + threadIdx.x;
  if (i >= K * Mo) return;
  int k = i / Mo, m = i - k * Mo;
  float v = W[i];
  unsigned short h = f2bf(v);
  hi[(size_t)m * K + k] = h;
  lo[(size_t)m * K + k] = f2bf(v - bf2f(h));
}

// ---------------- GEMM + fused attention-score partials; C written as bf16 hi ----------------
// Chi[M][Ncols] = Ah[M][K] @ (BThi+BTlo)[Ncols][K]^T ; el/er += C·al / C·ar (atomic)
// 2-MFMA scheme: Ah·Bh + Ah·Bl (B = weights, kept to ~f32; A single bf16 rounding)
template <int NF>
__global__ __launch_bounds__(256) void gemm_split(
    const unsigned short* __restrict__ Ahi,
    const unsigned short* __restrict__ BThi, const unsigned short* __restrict__ BTlo,
    unsigned short* __restrict__ Chi,
    const float* __restrict__ alv, const float* __restrict__ arv,
    float* __restrict__ el, float* __restrict__ er, int Hn, int M, int K, int Ncols) {
  constexpr int BN = NF * 32;
  __shared__ unsigned short As[128][40];   // hi at [0,32), stride 80B
  __shared__ unsigned short Bs[BN][88];    // hi at [0,32), lo at [48,80)
  const int tid = threadIdx.x;
  const int row0 = blockIdx.x * 128;
  const int col0 = blockIdx.y * BN;
  const int wid = tid >> 6, lane = tid & 63;
  const int wm = wid >> 1, wn = wid & 1;
  const int l15 = lane & 15, lg = lane >> 4;
  f32x4 acc[4][NF];
#pragma unroll
  for (int m = 0; m < 4; ++m)
#pragma unroll
    for (int n = 0; n < NF; ++n) acc[m][n] = (f32x4){0.f, 0.f, 0.f, 0.f};

  const uint4 zero4 = {0u, 0u, 0u, 0u};
  for (int k0 = 0; k0 < K; k0 += 32) {
    {  // stage A (hi only): 128 rows x 4 kgroups
      int r = tid >> 2;
      const int kg = tid & 3;
#pragma unroll
      for (int it = 0; it < 2; ++it, r += 64) {
        const int grow = row0 + r;
        uint4 vh = zero4;
        if (grow < M) vh = *reinterpret_cast<const uint4*>(&Ahi[(size_t)grow * K + k0 + kg * 8]);
        *reinterpret_cast<uint4*>(&As[r][kg * 8]) = vh;
      }
    }
    {  // stage B hi+lo
      int r = tid >> 2;
      const int kg = tid & 3;
#pragma unroll
      for (int it = 0; it < BN / 64; ++it, r += 64) {
        const int gcol = col0 + r;
        uint4 vh = *reinterpret_cast<const uint4*>(&BThi[(size_t)gcol * K + k0 + kg * 8]);
        uint4 vl = *reinterpret_cast<const uint4*>(&BTlo[(size_t)gcol * K + k0 + kg * 8]);
        *reinterpret_cast<uint4*>(&Bs[r][kg * 8]) = vh;
        *reinterpret_cast<uint4*>(&Bs[r][48 + kg * 8]) = vl;
      }
    }
    __syncthreads();
    bf16x8 ah[4];
#pragma unroll
    for (int m = 0; m < 4; ++m) {
      const int row = wm * 64 + m * 16 + l15;
      ah[m] = *reinterpret_cast<const bf16x8*>(&As[row][lg * 8]);
    }
#pragma unroll
    for (int n = 0; n < NF; ++n) {
      const int col = wn * (NF * 16) + n * 16 + l15;
      bf16x8 bh = *reinterpret_cast<const bf16x8*>(&Bs[col][lg * 8]);
      bf16x8 bl = *reinterpret_cast<const bf16x8*>(&Bs[col][48 + lg * 8]);
#pragma unroll
      for (int m = 0; m < 4; ++m) {
        acc[m][n] = __builtin_amdgcn_mfma_f32_16x16x32_bf16(ah[m], bh, acc[m][n], 0, 0, 0);
        acc[m][n] = __builtin_amdgcn_mfma_f32_16x16x32_bf16(ah[m], bl, acc[m][n], 0, 0, 0);
      }
    }
    __syncthreads();
  }
  // wave's NF col-frags all lie in one head (NF*16 <= 64)
  const int hw = (col0 + wn * (NF * 16)) >> 6;
  float alw[NF], arw[NF];
#pragma unroll
  for (int n = 0; n < NF; ++n) {
    const int colg = col0 + wn * (NF * 16) + n * 16 + l15;
    alw[n] = alv[colg];
    arw[n] = arv[colg];
  }
  float pel[4][4] = {{0.f}}, per_[4][4] = {{0.f}};
  // epilogue: C/D layout col=lane&15, row=(lane>>4)*4+j
#pragma unroll
  for (int m = 0; m < 4; ++m) {
#pragma unroll
    for (int n = 0; n < NF; ++n) {
      const int col = col0 + wn * (NF * 16) + n * 16 + l15;
#pragma unroll
      for (int j = 0; j < 4; ++j) {
        const int row = row0 + wm * 64 + m * 16 + lg * 4 + j;
        const float v = acc[m][n][j];
        if (row < M) Chi[(size_t)row * Ncols + col] = f2bf(v);
        pel[m][j] = fmaf(v, alw[n], pel[m][j]);
        per_[m][j] = fmaf(v, arw[n], per_[m][j]);
      }
    }
  }
#pragma unroll
  for (int m = 0; m < 4; ++m) {
#pragma unroll
    for (int j = 0; j < 4; ++j) {
      float vl = pel[m][j], vr = per_[m][j];
#pragma unroll
      for (int off = 1; off < 16; off <<= 1) {
        vl += __shfl_xor(vl, off);
        vr += __shfl_xor(vr, off);
      }
      if (l15 == 0) {
        const int row = row0 + wm * 64 + m * 16 + lg * 4 + j;
        if (row < M) {
          atomicAdd(&el[(size_t)row * Hn + hw], vl);
          atomicAdd(&er[(size_t)row * Hn + hw], vr);
        }
      }
    }
  }
}

// ---------------- CSR build ----------------
__global__ void hist_kernel(const int* __restrict__ dst, int* __restrict__ deg, int E) {
  int i = blockIdx.x * blockDim.x + threadIdx.x;
  if (i < E) atomicAdd(&deg[dst[i]], 1);
}

__global__ void scan1(const int* __restrict__ deg, int* __restrict__ offs,
                      int* __restrict__ bsums, int N) {
  __shared__ int tmp[256];
  const int tid = threadIdx.x;
  const int i = blockIdx.x * 256 + tid;
  int v = (i < N) ? deg[i] : 0;
  tmp[tid] = v;
  __syncthreads();
  for (int d = 1; d < 256; d <<= 1) {
    int t = (tid >= d) ? tmp[tid - d] : 0;
    __syncthreads();
    tmp[tid] += t;
    __syncthreads();
  }
  if (i < N) offs[i] = tmp[tid] - v;
  if (tid == 255) bsums[blockIdx.x] = tmp[255];
}

__global__ void scan2(int* __restrict__ bsums, int nb) {
  __shared__ int tmp[256];
  const int tid = threadIdx.x;
  int v = (tid < nb) ? bsums[tid] : 0;
  tmp[tid] = v;
  __syncthreads();
  for (int d = 1; d < 256; d <<= 1) {
    int t = (tid >= d) ? tmp[tid - d] : 0;
    __syncthreads();
    tmp[tid] += t;
    __syncthreads();
  }
  if (tid < nb) bsums[tid] = tmp[tid] - v;
}

__global__ void scan3(int* __restrict__ offs, const int* __restrict__ bsums, int N, int E) {
  const int i = blockIdx.x * 256 + threadIdx.x;
  if (i < N) offs[i] += bsums[blockIdx.x];
  if (i == 0) offs[N] = E;
}

__global__ void scatter_kernel(const int* __restrict__ src, const int* __restrict__ dst,
                               const int* __restrict__ offs, int* __restrict__ cursor,
                               int* __restrict__ csr_src, int E) {
  int i = blockIdx.x * blockDim.x + threadIdx.x;
  if (i >= E) return;
  int dn = dst[i];
  int pos = atomicAdd(&cursor[dn], 1);
  csr_src[offs[dn] + pos] = src[i];
}

// ---------------- alpha: 16-lane group per dst node (4 nodes/wave) ----------------
template <int H>
__global__ void alpha16(const int* __restrict__ offs, const int* __restrict__ csr_src,
                        const float* __restrict__ el, const float* __restrict__ er,
                        float* __restrict__ abuf, int N) {
  const int w = (int)((blockIdx.x * (size_t)blockDim.x + threadIdx.x) >> 6);
  const int lane = threadIdx.x & 63;
  const int g = lane >> 4, q = lane & 15;
  const int node = w * 4 + g;
  int beg = 0, end = 0;
  float erh[H];
#pragma unroll
  for (int h = 0; h < H; ++h) erh[h] = 0.f;
  if (node < N) {
    beg = offs[node]; end = offs[node + 1];
    if constexpr (H == 4) {
      float4 t = *reinterpret_cast<const float4*>(&er[(size_t)node * 4]);
      erh[0] = t.x; erh[1] = t.y; erh[2] = t.z; erh[3] = t.w;
    } else {
      erh[0] = er[node];
    }
  }
  float m[H], s[H];
#pragma unroll
  for (int h = 0; h < H; ++h) { m[h] = -INFINITY; s[h] = 0.f; }
  for (int i0 = beg; i0 < end; i0 += 16) {
    const int i = i0 + q;
    const bool valid = i < end;
    const int sn = valid ? csr_src[i] : 0;
    float e[H];
    if constexpr (H == 4) {
      float4 v = *reinterpret_cast<const float4*>(&el[(size_t)sn * 4]);
      e[0] = v.x + erh[0]; e[1] = v.y + erh[1]; e[2] = v.z + erh[2]; e[3] = v.w + erh[3];
    } else {
      e[0] = el[sn] + erh[0];
    }
#pragma unroll
    for (int h = 0; h < H; ++h) {
      e[h] = e[h] > 0.f ? e[h] : NEG_SLOPE * e[h];
      if (!valid) e[h] = -INFINITY;
      float cm = e[h];
#pragma unroll
      for (int off = 1; off < 16; off <<= 1) cm = fmaxf(cm, __shfl_xor(cm, off));
      const float nm = fmaxf(m[h], cm);
      float cs = __expf(e[h] - nm);
#pragma unroll
      for (int off = 1; off < 16; off <<= 1) cs += __shfl_xor(cs, off);
      s[h] = s[h] * __expf(m[h] - nm) + cs;
      m[h] = nm;
    }
  }
  float inv[H];
#pragma unroll
  for (int h = 0; h < H; ++h) inv[h] = 1.f / fmaxf(s[h], 1e-9f);
  for (int i0 = beg; i0 < end; i0 += 16) {
    const int i = i0 + q;
    if (i < end) {
      const int sn = csr_src[i];
      float e[H];
      if constexpr (H == 4) {
        float4 v = *reinterpret_cast<const float4*>(&el[(size_t)sn * 4]);
        e[0] = v.x + erh[0]; e[1] = v.y + erh[1]; e[2] = v.z + erh[2]; e[3] = v.w + erh[3];
      } else {
        e[0] = el[sn] + erh[0];
      }
#pragma unroll
      for (int h = 0; h < H; ++h) {
        e[h] = e[h] > 0.f ? e[h] : NEG_SLOPE * e[h];
        e[h] = __expf(e[h] - m[h]) * inv[h];
      }
      if constexpr (H == 4) {
        float4 o; o.x = e[0]; o.y = e[1]; o.z = e[2]; o.w = e[3];
        *reinterpret_cast<float4*>(&abuf[(size_t)i * 4]) = o;
      } else {
        abuf[i] = e[0];
      }
    }
  }
}

// ---------------- aggregate H=4: one wave/node, bf16 gather, 8-edge unroll ----------------
// lane owns feature (h*64 + lane) for h=0..3; reads Chi only (hi bf16 of feat)
template <bool SPLIT>
__global__ void aggregate_h4(const int* __restrict__ offs, const int* __restrict__ csr_src,
                             const unsigned short* __restrict__ featH, const float4* __restrict__ abuf,
                             const float* __restrict__ bias, float* __restrict__ outf,
                             unsigned short* __restrict__ outhi, int N) {
  const int wid = (int)((blockIdx.x * (size_t)blockDim.x + threadIdx.x) >> 6);
  const int lane = threadIdx.x & 63;
  if (wid >= N) return;
  const int beg = offs[wid], end = offs[wid + 1];
  float a0 = 0.f, a1 = 0.f, a2 = 0.f, a3 = 0.f;
  int i = beg;
  for (; i + 7 < end; i += 8) {
    int sn[8]; float4 w[8];
    unsigned short u0[8], u1[8], u2[8], u3[8];
#pragma unroll
    for (int u = 0; u < 8; ++u) sn[u] = csr_src[i + u];
#pragma unroll
    for (int u = 0; u < 8; ++u) w[u] = abuf[i + u];
#pragma unroll
    for (int u = 0; u < 8; ++u) {
      const unsigned short* f = &featH[(size_t)sn[u] * 256 + lane];
      u0[u] = f[0]; u1[u] = f[64]; u2[u] = f[128]; u3[u] = f[192];
    }
#pragma unroll
    for (int u = 0; u < 8; ++u) {
      a0 = fmaf(w[u].x, bf2f(u0[u]), a0);
      a1 = fmaf(w[u].y, bf2f(u1[u]), a1);
      a2 = fmaf(w[u].z, bf2f(u2[u]), a2);
      a3 = fmaf(w[u].w, bf2f(u3[u]), a3);
    }
  }
  for (; i < end; ++i) {
    const int sn = csr_src[i];
    const float4 w = abuf[i];
    const unsigned short* f = &featH[(size_t)sn * 256 + lane];
    a0 = fmaf(w.x, bf2f(f[0]), a0);
    a1 = fmaf(w.y, bf2f(f[64]), a1);
    a2 = fmaf(w.z, bf2f(f[128]), a2);
    a3 = fmaf(w.w, bf2f(f[192]), a3);
  }
  const float o0 = a0 + bias[lane];
  const float o1 = a1 + bias[64 + lane];
  const float o2 = a2 + bias[128 + lane];
  const float o3 = a3 + bias[192 + lane];
  const size_t base = (size_t)wid * 256 + lane;
  if constexpr (SPLIT) {
    outhi[base] = f2bf(o0);
    outhi[base + 64] = f2bf(o1);
    outhi[base + 128] = f2bf(o2);
    outhi[base + 192] = f2bf(o3);
  } else {
    outf[base] = o0; outf[base + 64] = o1; outf[base + 128] = o2; outf[base + 192] = o3;
  }
}

// ---------------- aggregate H=1: 16-lane groups, 4 edges/iter, bf16 gather ----------------
__global__ void aggregate1(const int* __restrict__ offs, const int* __restrict__ csr_src,
                           const unsigned short* __restrict__ featH, const float* __restrict__ abuf,
                           const float* __restrict__ bias, float* __restrict__ outf, int N) {
  const int wid = (int)((blockIdx.x * (size_t)blockDim.x + threadIdx.x) >> 6);
  const int lane = threadIdx.x & 63;
  if (wid >= N) return;
  const int beg = offs[wid], end = offs[wid + 1];
  const int g = lane >> 4, q = lane & 15;
  float4 acc = make_float4(0.f, 0.f, 0.f, 0.f);
  for (int i0 = beg; i0 < end; i0 += 4) {
    const int e = i0 + g;
    if (e < end) {
      const int sn = csr_src[e];
      const float a = abuf[e];
      const ushort4 u = *reinterpret_cast<const ushort4*>(&featH[(size_t)sn * 64 + q * 4]);
      acc.x = fmaf(a, bf2f(u.x), acc.x);
      acc.y = fmaf(a, bf2f(u.y), acc.y);
      acc.z = fmaf(a, bf2f(u.z), acc.z);
      acc.w = fmaf(a, bf2f(u.w), acc.w);
    }
  }
#pragma unroll
  for (int off = 16; off <= 32; off <<= 1) {
    acc.x += __shfl_xor(acc.x, off);
    acc.y += __shfl_xor(acc.y, off);
    acc.z += __shfl_xor(acc.z, off);
    acc.w += __shfl_xor(acc.w, off);
  }
  if (lane < 16) {
    const float4 b4 = *reinterpret_cast<const float4*>(&bias[q * 4]);
    float4 o = make_float4(acc.x + b4.x, acc.y + b4.y, acc.z + b4.z, acc.w + b4.w);
    *reinterpret_cast<float4*>(&outf[(size_t)wid * 64 + q * 4]) = o;
  }
}

// ---------------- tail: ids as float ----------------
__global__ void copy_ids(const int* __restrict__ ids, float* __restrict__ out, int n) {
  int i = blockIdx.x * blockDim.x + threadIdx.x;
  if (i < n) out[i] = (float)ids[i];
}

extern "C" void kernel_launch(void* const* d_in, const int* in_sizes, int n_in,
                              void* d_out, int out_size, void* d_ws, size_t ws_size,
                              hipStream_t stream) {
  const float* h   = (const float*)d_in[0];
  const int* src   = (const int*)d_in[1];
  const int* dst   = (const int*)d_in[2];
  const int* ids   = (const int*)d_in[3];
  const float* W0  = (const float*)d_in[4];
  const float* al0 = (const float*)d_in[5];
  const float* ar0 = (const float*)d_in[6];
  const float* b0  = (const float*)d_in[7];
  const float* W1  = (const float*)d_in[8];
  const float* al1 = (const float*)d_in[9];
  const float* ar1 = (const float*)d_in[10];
  const float* b1  = (const float*)d_in[11];
  const float* W2  = (const float*)d_in[12];
  const float* al2 = (const float*)d_in[13];
  const float* ar2 = (const float*)d_in[14];
  const float* b2  = (const float*)d_in[15];

  const int Din = 256, HF = 256, F2 = 64;
  const int N = in_sizes[0] / Din;        // 50000
  const int E = in_sizes[1];              // 800000
  const int NIDS = in_sizes[3];           // 1024

  // workspace layout (16B-aligned chunks)
  char* p = (char*)d_ws;
  unsigned short* Chi = (unsigned short*)p; p += (size_t)N * 256 * 2;  // feat bf16 hi
  unsigned short* Ahi = (unsigned short*)p; p += (size_t)N * 256 * 2;  // GEMM input hi
  unsigned short* W0hi = (unsigned short*)p; p += (size_t)HF * Din * 2;
  unsigned short* W0lo = (unsigned short*)p; p += (size_t)HF * Din * 2;
  unsigned short* W1hi = (unsigned short*)p; p += (size_t)HF * HF * 2;
  unsigned short* W1lo = (unsigned short*)p; p += (size_t)HF * HF * 2;
  unsigned short* W2hi = (unsigned short*)p; p += (size_t)F2 * HF * 2;
  unsigned short* W2lo = (unsigned short*)p; p += (size_t)F2 * HF * 2;
  float* el   = (float*)p;             p += (size_t)N * 4 * 4;
  float* er   = (float*)p;             p += (size_t)N * 4 * 4;
  float* abuf = (float*)p;             p += (size_t)E * 4 * 4;
  int* deg    = (int*)p;               p += (size_t)N * 4;
  int* offs   = (int*)p;               p += (size_t)(N + 16) * 4;
  int* bsums  = (int*)p;               p += 256 * 4;
  int* csr_src = (int*)p;              p += (size_t)E * 4;

  float* outp = (float*)d_out;
  dim3 blk(256);
  const int nb = cdiv(N, 256);
  const int nwAlpha = cdiv(cdiv(N, 4) * 64, 256);

  // ---------------- pre-passes: splits ----------------
  split_hi_kernel<<<cdiv(N * 256 / 4, 256), blk, 0, stream>>>(h, Ahi, N * 256 / 4);
  splitT_kernel<<<cdiv(Din * HF, 256), blk, 0, stream>>>(W0, W0hi, W0lo, Din, HF);
  splitT_kernel<<<cdiv(HF * HF, 256), blk, 0, stream>>>(W1, W1hi, W1lo, HF, HF);
  splitT_kernel<<<cdiv(HF * F2, 256), blk, 0, stream>>>(W2, W2hi, W2lo, HF, F2);

  // ---------------- CSR build (shared by all 3 layers) ----------------
  hipMemsetAsync(deg, 0, (size_t)N * 4, stream);
  hist_kernel<<<cdiv(E, 256), blk, 0, stream>>>(dst, deg, E);
  scan1<<<nb, blk, 0, stream>>>(deg, offs, bsums, N);
  scan2<<<1, blk, 0, stream>>>(bsums, nb);
  scan3<<<nb, blk, 0, stream>>>(offs, bsums, N, E);
  hipMemsetAsync(deg, 0, (size_t)N * 4, stream);
  scatter_kernel<<<cdiv(E, 256), blk, 0, stream>>>(src, dst, offs, deg, csr_src, E);

  // ---------------- layer 0 (H=4): Ahi -> Chi -> Ahi ----------------
  {
    hipMemsetAsync(el, 0, (size_t)N * 4 * 4 * 2, stream);   // el+er contiguous
    dim3 g(cdiv(N, 128), HF / 128);
    gemm_split<4><<<g, blk, 0, stream>>>(Ahi, W0hi, W0lo, Chi, al0, ar0, el, er, 4, N, Din, HF);
    alpha16<4><<<nwAlpha, blk, 0, stream>>>(offs, csr_src, el, er, abuf, N);
    aggregate_h4<true><<<cdiv(N * 64, 256), blk, 0, stream>>>(offs, csr_src, Chi, (const float4*)abuf,
                                                              b0, nullptr, Ahi, N);
  }
  // ---------------- layer 1 (H=4) ----------------
  {
    hipMemsetAsync(el, 0, (size_t)N * 4 * 4 * 2, stream);
    dim3 g(cdiv(N, 128), HF / 128);
    gemm_split<4><<<g, blk, 0, stream>>>(Ahi, W1hi, W1lo, Chi, al1, ar1, el, er, 4, N, HF, HF);
    alpha16<4><<<nwAlpha, blk, 0, stream>>>(offs, csr_src, el, er, abuf, N);
    aggregate_h4<true><<<cdiv(N * 64, 256), blk, 0, stream>>>(offs, csr_src, Chi, (const float4*)abuf,
                                                              b1, nullptr, Ahi, N);
  }
  // ---------------- layer 2 (H=1): -> d_out ----------------
  {
    hipMemsetAsync(el, 0, (size_t)N * 4 * 4 * 2, stream);
    dim3 g(cdiv(N, 128), 1);
    gemm_split<2><<<g, blk, 0, stream>>>(Ahi, W2hi, W2lo, Chi, al2, ar2, el, er, 1, N, HF, F2);
    alpha16<1><<<nwAlpha, blk, 0, stream>>>(offs, csr_src, el, er, abuf, N);
    aggregate1<<<cdiv(N * 64, 256), blk, 0, stream>>>(offs, csr_src, Chi, abuf, b2, outp, N);
  }
  // ---------------- tail ids ----------------
  copy_ids<<<cdiv(NIDS, 256), blk, 0, stream>>>(ids, outp + (size_t)N * F2, NIDS);
}